// Round 3
// baseline (1018.254 us; speedup 1.0000x reference)
//
#include <hip/hip_runtime.h>
#include <cstdint>
#include <cstddef>

#define PP 3
#define NN 6144
#define BB 3072
#define FF 512
#define HH 8
#define OO 32
#define DD 256
#define AA 128
#define M0 10.0f
#define LOG2E 1.44269504088896340736f
#define KSPLIT 4
#define KRANGE (BB/KSPLIT)
#define NT (KRANGE/32)

typedef __attribute__((ext_vector_type(8))) short short8;
typedef __attribute__((ext_vector_type(4))) float f32x4;

__device__ __forceinline__ unsigned short f2bf(float x){
  union { float f; unsigned u; } v; v.f = x;
  unsigned r = v.u + 0x7fffu + ((v.u >> 16) & 1u);
  return (unsigned short)(r >> 16);
}

__device__ __forceinline__ float fexp2(float x){
#if __has_builtin(__builtin_amdgcn_exp2f)
  return __builtin_amdgcn_exp2f(x);
#else
  return exp2f(x);
#endif
}

__device__ __forceinline__ f32x4 mfma16(short8 a, short8 b, f32x4 c){
  return __builtin_amdgcn_mfma_f32_16x16x32_bf16(a, b, c, 0, 0, 0);
}

// K1: per-head projection -> seqT bf16 [i][h][o][B] (k-contiguous for MFMA B-frags),
// f1g [i][h][B] and f2g [i][h][B] pre-scaled by LOG2E (exp folded to exp2 in k_attn).
__global__ __launch_bounds__(256) void k_seq(
    const float* __restrict__ features, const int* __restrict__ batch_nodes,
    const float* __restrict__ Wc1, const float* __restrict__ bc1,
    const float* __restrict__ a1, const float* __restrict__ ab1,
    const float* __restrict__ a2, const float* __restrict__ ab2,
    unsigned short* __restrict__ seqT, float* __restrict__ f1g, float* __restrict__ f2g)
{
  int i = blockIdx.z, h = blockIdx.y, b0 = blockIdx.x * 8;
  int t = threadIdx.x;
  __shared__ float xs[8][64];
  __shared__ float wt[64][33];
  __shared__ float a1s[32], a2s[32], bcs[32];
  __shared__ float sst[32][9];
  const float* W = Wc1 + (size_t)(i*HH + h) * OO * 64;
  for (int e = t; e < 2048; e += 256){ int o = e >> 6, c = e & 63; wt[c][o] = W[e]; }
  if (t < 32){
    a1s[t] = a1[(i*HH+h)*OO + t];
    a2s[t] = a2[(i*HH+h)*OO + t];
    bcs[t] = bc1[(i*HH+h)*OO + t];
  }
  for (int e = t; e < 512; e += 256){
    int bl = e >> 6, c = e & 63;
    int row = batch_nodes[i*BB + b0 + bl];
    xs[bl][c] = features[((size_t)i*NN + row)*FF + h*64 + c];
  }
  __syncthreads();
  int bl = t >> 5, o = t & 31;
  float acc = bcs[o];
  #pragma unroll
  for (int c = 0; c < 64; c++) acc += xs[bl][c] * wt[c][o];
  float v1 = acc * a1s[o], v2 = acc * a2s[o];
  #pragma unroll
  for (int s = 16; s >= 1; s >>= 1){ v1 += __shfl_xor(v1, s); v2 += __shfl_xor(v2, s); }
  if (o == 0){
    f1g[(i*HH+h)*BB + b0 + bl] = (v1 + ab1[i*HH+h]) * LOG2E;
    f2g[(i*HH+h)*BB + b0 + bl] = (v2 + ab2[i*HH+h]) * LOG2E;
  }
  sst[o][bl] = acc;
  __syncthreads();
  {
    int o2 = t >> 3, b2 = t & 7;
    seqT[((size_t)(i*HH+h)*OO + o2)*BB + b0 + b2] = f2bf(sst[o2][b2]);
  }
}

// K2: PURE bias gather (LDS row staging: coalesced HBM reads, LDS random gather).
// Writes (bias - M0)*LOG2E so k_attn's exp argument is a bare exp2 operand.
__global__ __launch_bounds__(256) void k_gather(
    const float* __restrict__ biases, const int* __restrict__ batch_nodes,
    float* __restrict__ bbg, int i_base, int nbuf)
{
  int i = i_base + blockIdx.z;
  int q0 = blockIdx.x * 2;
  int t = threadIdx.x;
  __shared__ float rowbuf[2][NN];   // 48 KB -> 3 blocks/CU
  int r0 = batch_nodes[i*BB + q0];
  int r1 = batch_nodes[i*BB + q0 + 1];
  const float4* s0 = (const float4*)(biases + ((size_t)i*NN + r0)*NN);
  const float4* s1 = (const float4*)(biases + ((size_t)i*NN + r1)*NN);
  #pragma unroll
  for (int e = 0; e < NN/4; e += 256){
    ((float4*)rowbuf[0])[e + t] = s0[e + t];
    ((float4*)rowbuf[1])[e + t] = s1[e + t];
  }
  const int* ci = batch_nodes + i*BB;
  float* dst0 = bbg + ((size_t)(i % nbuf)*BB + q0)*BB;
  float* dst1 = dst0 + BB;
  __syncthreads();
  #pragma unroll 4
  for (int c = 0; c < BB; c += 256){
    int k = c + t;
    int col = ci[k];
    dst0[k] = (rowbuf[0][col] - M0) * LOG2E;
    dst1[k] = (rowbuf[1][col] - M0) * LOG2E;
  }
}

// K3: barrier-free PV matmul. Each wave loads its own 32x32 bias tile / f2 slice / seqT
// fragments straight from global (bbg L3-hot due to per-i interleaved launch order),
// 2-deep register pipeline, unnormalized p = exp2(shat), per-row partial sums Lp.
__global__ __launch_bounds__(256, 3) void k_attn(
    const float* __restrict__ bbg, const unsigned short* __restrict__ seqT,
    const float* __restrict__ f1g, const float* __restrict__ f2g,
    float* __restrict__ Lp, float* __restrict__ h1p, int i_base, int nbuf)
{
  int i = i_base + blockIdx.z;
  int ks = blockIdx.y;
  int q0 = blockIdx.x * 32;
  int kbase = ks * KRANGE;
  int t = threadIdx.x;
  int w = t >> 6, lane = t & 63;
  int qf = lane & 15, kq = lane >> 4;
  f32x4 acc[2][2][2] = {};           // [head][q_half][o_half]
  float Ls[2][2] = {{0.f,0.f},{0.f,0.f}};
  float f1r[2][2];
  #pragma unroll
  for (int hh = 0; hh < 2; hh++)
  #pragma unroll
  for (int qh = 0; qh < 2; qh++){
    int h = w*2 + hh;
    f1r[hh][qh] = f1g[(i*HH+h)*BB + q0 + qh*16 + qf];
  }
  const float* bbb = bbg + (size_t)(i % nbuf)*BB*BB;
  // per-lane base pointers (row fixed per lane; k advances by tile)
  const float* bbp0 = bbb + (size_t)(q0 + qf)*BB + kbase + kq*8;
  const float* bbp1 = bbp0 + (size_t)16*BB;
  const float* f2p0 = f2g + ((size_t)(i*HH + w*2 + 0))*BB + kbase + kq*8;
  const float* f2p1 = f2p0 + BB;
  const unsigned short* sq00 = seqT + ((size_t)(i*HH + w*2 + 0)*OO + qf)*BB + kbase + kq*8;
  const unsigned short* sq01 = sq00 + (size_t)16*BB;
  const unsigned short* sq10 = sq00 + (size_t)OO*BB;
  const unsigned short* sq11 = sq10 + (size_t)16*BB;

  struct Tile {
    f32x4 bb[2][2];   // [q_half][col4]
    f32x4 f2[2][2];   // [head][col4]
    short8 sq[2][2];  // [head][o_half]
  };
  auto loadt = [&](Tile &T, int d){
    #pragma unroll
    for (int c = 0; c < 2; c++){
      T.bb[0][c] = *(const f32x4*)(bbp0 + d + c*4);
      T.bb[1][c] = *(const f32x4*)(bbp1 + d + c*4);
      T.f2[0][c] = *(const f32x4*)(f2p0 + d + c*4);
      T.f2[1][c] = *(const f32x4*)(f2p1 + d + c*4);
    }
    T.sq[0][0] = *(const short8*)(sq00 + d);
    T.sq[0][1] = *(const short8*)(sq01 + d);
    T.sq[1][0] = *(const short8*)(sq10 + d);
    T.sq[1][1] = *(const short8*)(sq11 + d);
  };
  auto compt = [&](const Tile &T){
    #pragma unroll
    for (int hh = 0; hh < 2; hh++){
      short8 af0, af1;
      #pragma unroll
      for (int j = 0; j < 8; j++){
        float f2v = T.f2[hh][j>>2][j&3];
        float s0 = f1r[hh][0] + f2v;
        s0 = fmaxf(s0, 0.01f*s0) + T.bb[0][j>>2][j&3];   // leaky: 0.01>0 => max form
        float s1 = f1r[hh][1] + f2v;
        s1 = fmaxf(s1, 0.01f*s1) + T.bb[1][j>>2][j&3];
        float e0 = fexp2(s0);
        float e1 = fexp2(s1);
        Ls[hh][0] += e0; Ls[hh][1] += e1;
        af0[j] = (short)f2bf(e0);
        af1[j] = (short)f2bf(e1);
      }
      acc[hh][0][0] = mfma16(af0, T.sq[hh][0], acc[hh][0][0]);
      acc[hh][0][1] = mfma16(af0, T.sq[hh][1], acc[hh][0][1]);
      acc[hh][1][0] = mfma16(af1, T.sq[hh][0], acc[hh][1][0]);
      acc[hh][1][1] = mfma16(af1, T.sq[hh][1], acc[hh][1][1]);
    }
  };

  Tile ta, tb;
  loadt(ta, 0);
  for (int it = 0; it < NT; it += 2){
    loadt(tb, (it+1)*32);
    compt(ta);
    if (it + 2 < NT) loadt(ta, (it+2)*32);
    compt(tb);
  }

  // denominator partials: sum over the 4 kq lanes (lane^16, lane^32), one store per row/head
  #pragma unroll
  for (int hh = 0; hh < 2; hh++)
  #pragma unroll
  for (int qh = 0; qh < 2; qh++){
    float v = Ls[hh][qh];
    v += __shfl_xor(v, 16);
    v += __shfl_xor(v, 32);
    if (kq == 0)
      Lp[(((size_t)ks*PP + i)*HH + w*2 + hh)*BB + q0 + qh*16 + qf] = v;
  }
  // C/D: col(o) = lane&15, row(q) = (lane>>4)*4 + reg [m89-verified]
  #pragma unroll
  for (int hh = 0; hh < 2; hh++){
    int h = w*2 + hh;
    #pragma unroll
    for (int qh = 0; qh < 2; qh++)
    #pragma unroll
    for (int oh = 0; oh < 2; oh++)
    #pragma unroll
    for (int r = 0; r < 4; r++){
      int q = q0 + qh*16 + kq*4 + r;
      int o = qf + oh*16;
      h1p[(((size_t)ks*PP + i)*BB + q)*DD + h*OO + o] = acc[hh][qh][oh][r];
    }
  }
}

__global__ __launch_bounds__(256) void k_twm(const float* __restrict__ Wm, float* __restrict__ wmT){
  int e = blockIdx.x, d = threadIdx.x;
  wmT[(size_t)e*DD + d] = Wm[(size_t)d*DD + e];
}

// K4: sum 4 k-split partials, normalize by 1/L (softmax denom), elu, emb = h1 @ Wm.T + bm,
// RL scale, semantic attention, out.
__global__ __launch_bounds__(256) void k_final(
    const float* __restrict__ h1p, const float* __restrict__ Lp,
    const float* __restrict__ wmT, const float* __restrict__ bm,
    const float* __restrict__ RL, const float* __restrict__ w_omega, const float* __restrict__ b_omega,
    const float* __restrict__ u_omega, float* __restrict__ out)
{
  __shared__ float buf[48*256];
  __shared__ float wred[4][24];
  __shared__ float alph[3][16];
  __shared__ float linvs[48][8];
  const size_t PB = (size_t)PP*BB*DD;
  const size_t KL = (size_t)PP*HH*BB;
  int t = threadIdx.x;
  int lane = t & 63, w = t >> 6;
  int b0 = blockIdx.x * 16;
  for (int e = t; e < 48*8; e += 256){
    int pb = e >> 3, h = e & 7;
    int p = pb / 16, bl = pb & 15;
    size_t off = ((size_t)p*HH + h)*BB + b0 + bl;
    float L = Lp[off] + Lp[off+KL] + Lp[off+2*KL] + Lp[off+3*KL];
    linvs[pb][h] = 1.f / L;
  }
  __syncthreads();
  for (int e = t; e < 48*256; e += 256){
    int pb = e >> 8, d = e & 255;
    int p = pb / 16, bl = pb & 15;
    size_t off = ((size_t)p*BB + b0 + bl)*DD + d;
    float v = h1p[off] + h1p[off + PB] + h1p[off + 2*PB] + h1p[off + 3*PB];
    v *= linvs[pb][d >> 5];
    buf[e] = (v > 0.f) ? v : (__expf(v) - 1.f);   // elu
  }
  __syncthreads();
  float acc[48];
  #pragma unroll
  for (int x = 0; x < 48; x++) acc[x] = 0.f;
  for (int e = 0; e < 256; e += 4){
    float w0 = wmT[(e+0)*DD + t];
    float w1 = wmT[(e+1)*DD + t];
    float w2 = wmT[(e+2)*DD + t];
    float w3 = wmT[(e+3)*DD + t];
    #pragma unroll
    for (int pb = 0; pb < 48; pb++){
      float4 hv = *(const float4*)&buf[pb*256 + e];
      acc[pb] += hv.x*w0 + hv.y*w1 + hv.z*w2 + hv.w*w3;
    }
  }
  __syncthreads();
  {
    float bmv = bm[t];
    #pragma unroll
    for (int p = 0; p < 3; p++){
      float rl = RL[p];
      #pragma unroll
      for (int bl = 0; bl < 16; bl++)
        buf[(p*16+bl)*256 + t] = (acc[p*16+bl] + bmv) * rl;
    }
  }
  __syncthreads();
  int a = t & 127, g = t >> 7;
  float acc2[24];
  #pragma unroll
  for (int x = 0; x < 24; x++) acc2[x] = 0.f;
  for (int e = 0; e < 256; e += 4){
    float w0 = w_omega[(e+0)*AA + a];
    float w1 = w_omega[(e+1)*AA + a];
    float w2 = w_omega[(e+2)*AA + a];
    float w3 = w_omega[(e+3)*AA + a];
    #pragma unroll
    for (int p = 0; p < 3; p++){
      #pragma unroll
      for (int bl = 0; bl < 8; bl++){
        float4 iv = *(const float4*)&buf[(p*16 + g*8 + bl)*256 + e];
        acc2[p*8+bl] += iv.x*w0 + iv.y*w1 + iv.z*w2 + iv.w*w3;
      }
    }
  }
  {
    float bo = b_omega[a], uo = u_omega[a];
    #pragma unroll
    for (int x = 0; x < 24; x++){
      float v = tanhf(acc2[x] + bo) * uo;
      #pragma unroll
      for (int s = 32; s >= 1; s >>= 1) v += __shfl_xor(v, s);
      if (lane == 0) wred[w][x] = v;
    }
  }
  __syncthreads();
  if (t < 16){
    int b = t;
    int g2 = b >> 3, bl2 = b & 7;
    float vu[3];
    #pragma unroll
    for (int p = 0; p < 3; p++){
      int j = p*8 + bl2;
      vu[p] = wred[g2*2 + 0][j] + wred[g2*2 + 1][j];
    }
    float mx = fmaxf(vu[0], fmaxf(vu[1], vu[2]));
    float e0 = __expf(vu[0]-mx), e1 = __expf(vu[1]-mx), e2 = __expf(vu[2]-mx);
    float inv = 1.f / (e0+e1+e2);
    alph[0][b] = e0*inv; alph[1][b] = e1*inv; alph[2][b] = e2*inv;
  }
  __syncthreads();
  #pragma unroll
  for (int bl = 0; bl < 16; bl++){
    float o = buf[(0*16+bl)*256 + t]*alph[0][bl]
            + buf[(1*16+bl)*256 + t]*alph[1][bl]
            + buf[(2*16+bl)*256 + t]*alph[2][bl];
    out[(size_t)(b0+bl)*DD + t] = o;
  }
}

extern "C" void kernel_launch(void* const* d_in, const int* in_sizes, int n_in,
                              void* d_out, int out_size, void* d_ws, size_t ws_size,
                              hipStream_t stream)
{
  const float* features = (const float*)d_in[0];
  const float* biases   = (const float*)d_in[1];
  const int*   batch_nodes = (const int*)d_in[2];
  const float* RL   = (const float*)d_in[3];
  const float* Wc1  = (const float*)d_in[4];
  const float* bc1  = (const float*)d_in[5];
  const float* a1   = (const float*)d_in[6];
  const float* ab1  = (const float*)d_in[7];
  const float* a2   = (const float*)d_in[8];
  const float* ab2  = (const float*)d_in[9];
  const float* Wm   = (const float*)d_in[10];
  const float* bm   = (const float*)d_in[11];
  const float* w_omega = (const float*)d_in[12];
  const float* b_omega = (const float*)d_in[13];
  const float* u_omega = (const float*)d_in[14];
  float* out = (float*)d_out;

  size_t sz_bbg1 = (size_t)BB*BB*4;
  size_t sz_seqT = (size_t)PP*HH*OO*BB*2;
  size_t sz_f    = (size_t)PP*HH*BB*4;
  size_t sz_h1   = (size_t)PP*BB*DD*4;
  size_t sz_wmT  = (size_t)DD*DD*4;
  size_t sz_Lp   = (size_t)KSPLIT*PP*HH*BB*4;
  size_t fixed = sz_seqT + 2*sz_f + (size_t)KSPLIT*sz_h1 + sz_wmT + sz_Lp + 16*256;
  int nbuf = (ws_size >= fixed + 3*sz_bbg1 + 256) ? 3 : 1;   // constant per problem -> graph-safe

  char* p = (char*)d_ws;
  auto take = [&](size_t bytes)->char*{ char* r = p; p += (bytes + 255) & ~(size_t)255; return r; };
  float* bbg  = (float*)take(sz_bbg1 * (size_t)nbuf);
  unsigned short* seqT = (unsigned short*)take(sz_seqT);
  float* f1g  = (float*)take(sz_f);
  float* f2g  = (float*)take(sz_f);
  float* Lp   = (float*)take(sz_Lp);
  float* h1p  = (float*)take(sz_h1 * (size_t)KSPLIT);
  float* wmT  = (float*)take(sz_wmT);

  k_twm<<<dim3(DD), dim3(DD), 0, stream>>>(Wm, wmT);
  k_seq<<<dim3(BB/8, HH, PP), dim3(256), 0, stream>>>(features, batch_nodes, Wc1, bc1, a1, ab1, a2, ab2, seqT, f1g, f2g);
  // Per-relation interleave: attn(i) runs immediately after gather(i), so bbg slot i
  // (37.7 MB << 256 MB L3) is L3-hot for attn's latency-bound tile reads.
  for (int r = 0; r < PP; r++){
    k_gather<<<dim3(BB/2, 1, 1), dim3(256), 0, stream>>>(biases, batch_nodes, bbg, r, nbuf);
    k_attn<<<dim3(BB/32, KSPLIT, 1), dim3(256), 0, stream>>>(bbg, seqT, f1g, f2g, Lp, h1p, r, nbuf);
  }
  k_final<<<dim3(BB/16), dim3(256), 0, stream>>>(h1p, Lp, wmT, bm, RL, w_omega, b_omega, u_omega, out);
}

// Round 4
// 953.599 us; speedup vs baseline: 1.0678x; 1.0678x over previous
//
#include <hip/hip_runtime.h>
#include <cstdint>
#include <cstddef>

#define PP 3
#define NN 6144
#define BB 3072
#define FF 512
#define HH 8
#define OO 32
#define DD 256
#define AA 128
#define M0 10.0f
#define LOG2E 1.44269504088896340736f
#define KSPLIT 4
#define KRANGE (BB/KSPLIT)
#define NT (KRANGE/32)

typedef __attribute__((ext_vector_type(8))) short short8;
typedef __attribute__((ext_vector_type(4))) float f32x4;

__device__ __forceinline__ unsigned short f2bf(float x){
  union { float f; unsigned u; } v; v.f = x;
  unsigned r = v.u + 0x7fffu + ((v.u >> 16) & 1u);
  return (unsigned short)(r >> 16);
}

__device__ __forceinline__ float fexp2(float x){
#if __has_builtin(__builtin_amdgcn_exp2f)
  return __builtin_amdgcn_exp2f(x);
#else
  return exp2f(x);
#endif
}

__device__ __forceinline__ f32x4 mfma16(short8 a, short8 b, f32x4 c){
  return __builtin_amdgcn_mfma_f32_16x16x32_bf16(a, b, c, 0, 0, 0);
}

// K1: per-head projection -> seqT bf16 [i][h][o][B] (k-contiguous for MFMA B-frags),
// f1g [i][h][B] and f2g [i][h][B] pre-scaled by LOG2E (exp folded to exp2 in k_attn).
__global__ __launch_bounds__(256) void k_seq(
    const float* __restrict__ features, const int* __restrict__ batch_nodes,
    const float* __restrict__ Wc1, const float* __restrict__ bc1,
    const float* __restrict__ a1, const float* __restrict__ ab1,
    const float* __restrict__ a2, const float* __restrict__ ab2,
    unsigned short* __restrict__ seqT, float* __restrict__ f1g, float* __restrict__ f2g)
{
  int i = blockIdx.z, h = blockIdx.y, b0 = blockIdx.x * 8;
  int t = threadIdx.x;
  __shared__ float xs[8][64];
  __shared__ float wt[64][33];
  __shared__ float a1s[32], a2s[32], bcs[32];
  __shared__ float sst[32][9];
  const float* W = Wc1 + (size_t)(i*HH + h) * OO * 64;
  for (int e = t; e < 2048; e += 256){ int o = e >> 6, c = e & 63; wt[c][o] = W[e]; }
  if (t < 32){
    a1s[t] = a1[(i*HH+h)*OO + t];
    a2s[t] = a2[(i*HH+h)*OO + t];
    bcs[t] = bc1[(i*HH+h)*OO + t];
  }
  for (int e = t; e < 512; e += 256){
    int bl = e >> 6, c = e & 63;
    int row = batch_nodes[i*BB + b0 + bl];
    xs[bl][c] = features[((size_t)i*NN + row)*FF + h*64 + c];
  }
  __syncthreads();
  int bl = t >> 5, o = t & 31;
  float acc = bcs[o];
  #pragma unroll
  for (int c = 0; c < 64; c++) acc += xs[bl][c] * wt[c][o];
  float v1 = acc * a1s[o], v2 = acc * a2s[o];
  #pragma unroll
  for (int s = 16; s >= 1; s >>= 1){ v1 += __shfl_xor(v1, s); v2 += __shfl_xor(v2, s); }
  if (o == 0){
    f1g[(i*HH+h)*BB + b0 + bl] = (v1 + ab1[i*HH+h]) * LOG2E;
    f2g[(i*HH+h)*BB + b0 + bl] = (v2 + ab2[i*HH+h]) * LOG2E;
  }
  sst[o][bl] = acc;
  __syncthreads();
  {
    int o2 = t >> 3, b2 = t & 7;
    seqT[((size_t)(i*HH+h)*OO + o2)*BB + b0 + b2] = f2bf(sst[o2][b2]);
  }
}

// K2: PURE bias gather (LDS row staging: coalesced HBM reads, LDS random gather).
// Writes (bias - M0)*LOG2E so k_attn's exp argument is a bare exp2 operand.
__global__ __launch_bounds__(256) void k_gather(
    const float* __restrict__ biases, const int* __restrict__ batch_nodes,
    float* __restrict__ bbg, int i_base, int nbuf)
{
  int i = i_base + blockIdx.z;
  int q0 = blockIdx.x * 2;
  int t = threadIdx.x;
  __shared__ float rowbuf[2][NN];   // 48 KB -> 3 blocks/CU
  int r0 = batch_nodes[i*BB + q0];
  int r1 = batch_nodes[i*BB + q0 + 1];
  const float4* s0 = (const float4*)(biases + ((size_t)i*NN + r0)*NN);
  const float4* s1 = (const float4*)(biases + ((size_t)i*NN + r1)*NN);
  #pragma unroll
  for (int e = 0; e < NN/4; e += 256){
    ((float4*)rowbuf[0])[e + t] = s0[e + t];
    ((float4*)rowbuf[1])[e + t] = s1[e + t];
  }
  const int* ci = batch_nodes + i*BB;
  float* dst0 = bbg + ((size_t)(i % nbuf)*BB + q0)*BB;
  float* dst1 = dst0 + BB;
  __syncthreads();
  #pragma unroll 4
  for (int c = 0; c < BB; c += 256){
    int k = c + t;
    int col = ci[k];
    dst0[k] = (rowbuf[0][col] - M0) * LOG2E;
    dst1[k] = (rowbuf[1][col] - M0) * LOG2E;
  }
}

// K3: barrier-free PV matmul, 1 HEAD PER WAVE (lean registers -> 16 waves/CU for
// latency hiding per Little's law). Block = 4 waves = 4 heads; grid.y = KSPLIT*2
// covers the 2 head-groups. 2-deep register pipeline, unnormalized p = exp2(shat),
// per-row partial sums Lp; normalization deferred to k_final.
__global__ __launch_bounds__(256, 4) void k_attn(
    const float* __restrict__ bbg, const unsigned short* __restrict__ seqT,
    const float* __restrict__ f1g, const float* __restrict__ f2g,
    float* __restrict__ Lp, float* __restrict__ h1p, int i_base, int nbuf)
{
  int i = i_base + blockIdx.z;
  int yy = blockIdx.y;
  int ks = yy >> 1, hg = yy & 1;
  int q0 = blockIdx.x * 32;
  int kbase = ks * KRANGE;
  int t = threadIdx.x;
  int w = t >> 6, lane = t & 63;
  int h = hg*4 + w;                   // this wave's head
  int qf = lane & 15, kq = lane >> 4;
  f32x4 acc[2][2] = {};               // [q_half][o_half]
  float Ls[2] = {0.f, 0.f};
  float f1r[2];
  #pragma unroll
  for (int qh = 0; qh < 2; qh++)
    f1r[qh] = f1g[(i*HH+h)*BB + q0 + qh*16 + qf];
  const float* bbb = bbg + (size_t)(i % nbuf)*BB*BB;
  // per-lane base pointers (row fixed per lane; k advances by tile)
  const float* bbp0 = bbb + (size_t)(q0 + qf)*BB + kbase + kq*8;
  const float* bbp1 = bbp0 + (size_t)16*BB;
  const float* f2p  = f2g + ((size_t)(i*HH + h))*BB + kbase + kq*8;
  const unsigned short* sq0 = seqT + ((size_t)(i*HH + h)*OO + qf)*BB + kbase + kq*8;
  const unsigned short* sq1 = sq0 + (size_t)16*BB;

  struct Tile {
    f32x4 bb[2][2];   // [q_half][col4]
    f32x4 f2[2];      // [col4]
    short8 sq[2];     // [o_half]
  };
  auto loadt = [&](Tile &T, int d){
    #pragma unroll
    for (int c = 0; c < 2; c++){
      T.bb[0][c] = *(const f32x4*)(bbp0 + d + c*4);
      T.bb[1][c] = *(const f32x4*)(bbp1 + d + c*4);
      T.f2[c]    = *(const f32x4*)(f2p  + d + c*4);
    }
    T.sq[0] = *(const short8*)(sq0 + d);
    T.sq[1] = *(const short8*)(sq1 + d);
  };
  auto compt = [&](const Tile &T){
    short8 af0, af1;
    #pragma unroll
    for (int j = 0; j < 8; j++){
      float f2v = T.f2[j>>2][j&3];
      float s0 = f1r[0] + f2v;
      s0 = fmaxf(s0, 0.01f*s0) + T.bb[0][j>>2][j&3];   // leaky: 0.01>0 => max form
      float s1 = f1r[1] + f2v;
      s1 = fmaxf(s1, 0.01f*s1) + T.bb[1][j>>2][j&3];
      float e0 = fexp2(s0);
      float e1 = fexp2(s1);
      Ls[0] += e0; Ls[1] += e1;
      af0[j] = (short)f2bf(e0);
      af1[j] = (short)f2bf(e1);
    }
    acc[0][0] = mfma16(af0, T.sq[0], acc[0][0]);
    acc[0][1] = mfma16(af0, T.sq[1], acc[0][1]);
    acc[1][0] = mfma16(af1, T.sq[0], acc[1][0]);
    acc[1][1] = mfma16(af1, T.sq[1], acc[1][1]);
  };

  Tile ta, tb;
  loadt(ta, 0);
  for (int it = 0; it < NT; it += 2){
    loadt(tb, (it+1)*32);
    compt(ta);
    if (it + 2 < NT) loadt(ta, (it+2)*32);
    compt(tb);
  }

  // denominator partials: sum over the 4 kq lanes (lane^16, lane^32), one store per row
  #pragma unroll
  for (int qh = 0; qh < 2; qh++){
    float v = Ls[qh];
    v += __shfl_xor(v, 16);
    v += __shfl_xor(v, 32);
    if (kq == 0)
      Lp[(((size_t)ks*PP + i)*HH + h)*BB + q0 + qh*16 + qf] = v;
  }
  // C/D: col(o) = lane&15, row(q) = (lane>>4)*4 + reg [m89-verified]
  #pragma unroll
  for (int qh = 0; qh < 2; qh++)
  #pragma unroll
  for (int oh = 0; oh < 2; oh++)
  #pragma unroll
  for (int r = 0; r < 4; r++){
    int q = q0 + qh*16 + kq*4 + r;
    int o = qf + oh*16;
    h1p[(((size_t)ks*PP + i)*BB + q)*DD + h*OO + o] = acc[qh][oh][r];
  }
}

__global__ __launch_bounds__(256) void k_twm(const float* __restrict__ Wm, float* __restrict__ wmT){
  int e = blockIdx.x, d = threadIdx.x;
  wmT[(size_t)e*DD + d] = Wm[(size_t)d*DD + e];
}

// K4: sum 4 k-split partials, normalize by 1/L (softmax denom), elu, emb = h1 @ Wm.T + bm,
// RL scale, semantic attention, out.
__global__ __launch_bounds__(256) void k_final(
    const float* __restrict__ h1p, const float* __restrict__ Lp,
    const float* __restrict__ wmT, const float* __restrict__ bm,
    const float* __restrict__ RL, const float* __restrict__ w_omega, const float* __restrict__ b_omega,
    const float* __restrict__ u_omega, float* __restrict__ out)
{
  __shared__ float buf[48*256];
  __shared__ float wred[4][24];
  __shared__ float alph[3][16];
  __shared__ float linvs[48][8];
  const size_t PB = (size_t)PP*BB*DD;
  const size_t KL = (size_t)PP*HH*BB;
  int t = threadIdx.x;
  int lane = t & 63, w = t >> 6;
  int b0 = blockIdx.x * 16;
  for (int e = t; e < 48*8; e += 256){
    int pb = e >> 3, h = e & 7;
    int p = pb / 16, bl = pb & 15;
    size_t off = ((size_t)p*HH + h)*BB + b0 + bl;
    float L = Lp[off] + Lp[off+KL] + Lp[off+2*KL] + Lp[off+3*KL];
    linvs[pb][h] = 1.f / L;
  }
  __syncthreads();
  for (int e = t; e < 48*256; e += 256){
    int pb = e >> 8, d = e & 255;
    int p = pb / 16, bl = pb & 15;
    size_t off = ((size_t)p*BB + b0 + bl)*DD + d;
    float v = h1p[off] + h1p[off + PB] + h1p[off + 2*PB] + h1p[off + 3*PB];
    v *= linvs[pb][d >> 5];
    buf[e] = (v > 0.f) ? v : (__expf(v) - 1.f);   // elu
  }
  __syncthreads();
  float acc[48];
  #pragma unroll
  for (int x = 0; x < 48; x++) acc[x] = 0.f;
  for (int e = 0; e < 256; e += 4){
    float w0 = wmT[(e+0)*DD + t];
    float w1 = wmT[(e+1)*DD + t];
    float w2 = wmT[(e+2)*DD + t];
    float w3 = wmT[(e+3)*DD + t];
    #pragma unroll
    for (int pb = 0; pb < 48; pb++){
      float4 hv = *(const float4*)&buf[pb*256 + e];
      acc[pb] += hv.x*w0 + hv.y*w1 + hv.z*w2 + hv.w*w3;
    }
  }
  __syncthreads();
  {
    float bmv = bm[t];
    #pragma unroll
    for (int p = 0; p < 3; p++){
      float rl = RL[p];
      #pragma unroll
      for (int bl = 0; bl < 16; bl++)
        buf[(p*16+bl)*256 + t] = (acc[p*16+bl] + bmv) * rl;
    }
  }
  __syncthreads();
  int a = t & 127, g = t >> 7;
  float acc2[24];
  #pragma unroll
  for (int x = 0; x < 24; x++) acc2[x] = 0.f;
  for (int e = 0; e < 256; e += 4){
    float w0 = w_omega[(e+0)*AA + a];
    float w1 = w_omega[(e+1)*AA + a];
    float w2 = w_omega[(e+2)*AA + a];
    float w3 = w_omega[(e+3)*AA + a];
    #pragma unroll
    for (int p = 0; p < 3; p++){
      #pragma unroll
      for (int bl = 0; bl < 8; bl++){
        float4 iv = *(const float4*)&buf[(p*16 + g*8 + bl)*256 + e];
        acc2[p*8+bl] += iv.x*w0 + iv.y*w1 + iv.z*w2 + iv.w*w3;
      }
    }
  }
  {
    float bo = b_omega[a], uo = u_omega[a];
    #pragma unroll
    for (int x = 0; x < 24; x++){
      float v = tanhf(acc2[x] + bo) * uo;
      #pragma unroll
      for (int s = 32; s >= 1; s >>= 1) v += __shfl_xor(v, s);
      if (lane == 0) wred[w][x] = v;
    }
  }
  __syncthreads();
  if (t < 16){
    int b = t;
    int g2 = b >> 3, bl2 = b & 7;
    float vu[3];
    #pragma unroll
    for (int p = 0; p < 3; p++){
      int j = p*8 + bl2;
      vu[p] = wred[g2*2 + 0][j] + wred[g2*2 + 1][j];
    }
    float mx = fmaxf(vu[0], fmaxf(vu[1], vu[2]));
    float e0 = __expf(vu[0]-mx), e1 = __expf(vu[1]-mx), e2 = __expf(vu[2]-mx);
    float inv = 1.f / (e0+e1+e2);
    alph[0][b] = e0*inv; alph[1][b] = e1*inv; alph[2][b] = e2*inv;
  }
  __syncthreads();
  #pragma unroll
  for (int bl = 0; bl < 16; bl++){
    float o = buf[(0*16+bl)*256 + t]*alph[0][bl]
            + buf[(1*16+bl)*256 + t]*alph[1][bl]
            + buf[(2*16+bl)*256 + t]*alph[2][bl];
    out[(size_t)(b0+bl)*DD + t] = o;
  }
}

extern "C" void kernel_launch(void* const* d_in, const int* in_sizes, int n_in,
                              void* d_out, int out_size, void* d_ws, size_t ws_size,
                              hipStream_t stream)
{
  const float* features = (const float*)d_in[0];
  const float* biases   = (const float*)d_in[1];
  const int*   batch_nodes = (const int*)d_in[2];
  const float* RL   = (const float*)d_in[3];
  const float* Wc1  = (const float*)d_in[4];
  const float* bc1  = (const float*)d_in[5];
  const float* a1   = (const float*)d_in[6];
  const float* ab1  = (const float*)d_in[7];
  const float* a2   = (const float*)d_in[8];
  const float* ab2  = (const float*)d_in[9];
  const float* Wm   = (const float*)d_in[10];
  const float* bm   = (const float*)d_in[11];
  const float* w_omega = (const float*)d_in[12];
  const float* b_omega = (const float*)d_in[13];
  const float* u_omega = (const float*)d_in[14];
  float* out = (float*)d_out;

  size_t sz_bbg1 = (size_t)BB*BB*4;
  size_t sz_seqT = (size_t)PP*HH*OO*BB*2;
  size_t sz_f    = (size_t)PP*HH*BB*4;
  size_t sz_h1   = (size_t)PP*BB*DD*4;
  size_t sz_wmT  = (size_t)DD*DD*4;
  size_t sz_Lp   = (size_t)KSPLIT*PP*HH*BB*4;
  size_t fixed = sz_seqT + 2*sz_f + (size_t)KSPLIT*sz_h1 + sz_wmT + sz_Lp + 16*256;
  int nbuf = (ws_size >= fixed + 3*sz_bbg1 + 256) ? 3 : 1;   // constant per problem -> graph-safe

  char* p = (char*)d_ws;
  auto take = [&](size_t bytes)->char*{ char* r = p; p += (bytes + 255) & ~(size_t)255; return r; };
  float* bbg  = (float*)take(sz_bbg1 * (size_t)nbuf);
  unsigned short* seqT = (unsigned short*)take(sz_seqT);
  float* f1g  = (float*)take(sz_f);
  float* f2g  = (float*)take(sz_f);
  float* Lp   = (float*)take(sz_Lp);
  float* h1p  = (float*)take(sz_h1 * (size_t)KSPLIT);
  float* wmT  = (float*)take(sz_wmT);

  k_twm<<<dim3(DD), dim3(DD), 0, stream>>>(Wm, wmT);
  k_seq<<<dim3(BB/8, HH, PP), dim3(256), 0, stream>>>(features, batch_nodes, Wc1, bc1, a1, ab1, a2, ab2, seqT, f1g, f2g);
  int nloop = (nbuf == 3) ? 1 : 3;
  int z = (nbuf == 3) ? 3 : 1;
  for (int r = 0; r < nloop; r++){
    k_gather<<<dim3(BB/2, 1, z), dim3(256), 0, stream>>>(biases, batch_nodes, bbg, r, nbuf);
    k_attn<<<dim3(BB/32, KSPLIT*2, z), dim3(256), 0, stream>>>(bbg, seqT, f1g, f2g, Lp, h1p, r, nbuf);
  }
  k_final<<<dim3(BB/16), dim3(256), 0, stream>>>(h1p, Lp, wmT, bm, RL, w_omega, b_omega, u_omega, out);
}